// Round 1
// baseline (68.337 us; speedup 1.0000x reference)
//
#include <hip/hip_runtime.h>
#include <math.h>

// B=64, C=256, H=W=16 (HW=256), HEADS=8, HEAD_DIM=256, HID=2048, TEMB=512
// Key identity: the reference einsum 'bhnm,bhcl->bhml' contracts n and c
// independently => softmax terms sum to 1 => q,k irrelevant; output before
// out_w projection is SC^2 * column-sum of v, constant over spatial dims.

#define NB 64
#define NC 256
#define NHW 256
#define NHEADS 8
#define NHID 2048
#define NTEMB 512

static constexpr float EPSV = 1e-6f;
static constexpr float SC2 = 1.0f / 256.0f;   // SC^2, SC = 256^-0.5

// ---------------------------------------------------------------- prep ----
// blocks 0..127  : silu_t[t*64+b] = silu(time_emb[b,t])           (transposed)
// blocks 128..191: wvp[(head*8+chunk)*256+ci] = partial column-sum of the
//                  v-block of qkv_w (rows 4096+head*256+chunk*32 .. +32)
__global__ void k_prep(const float* __restrict__ temb,
                       const float* __restrict__ qkv_w,
                       float* __restrict__ silu_t,
                       float* __restrict__ wvp) {
    int blk = blockIdx.x, tid = threadIdx.x;
    if (blk < 128) {
        int i = blk * 256 + tid;          // i = t*64 + b
        int t = i >> 6, b = i & 63;
        float v = temb[b * NTEMB + t];
        silu_t[i] = v / (1.0f + expf(-v));
    } else {
        int w = blk - 128;                // 0..63
        int head = w >> 3, chunk = w & 7;
        const float* base =
            qkv_w + (size_t)(2 * NHID + head * 256 + chunk * 32) * NC + tid;
        float s = 0.f;
#pragma unroll
        for (int c = 0; c < 32; ++c) s += base[c * NC];
        wvp[w * 256 + tid] = s;
    }
}

// ----------------------------------------------------------------- mod ----
// scsh[b*512 + j] = silu(temb[b]) . mlp_w[j] + mlp_b[j]
// lanes = b (coalesced silu_t reads), wave = j (uniform mlp_w reads)
__global__ void k_mod(const float* __restrict__ silu_t,
                      const float* __restrict__ mlp_w,
                      const float* __restrict__ mlp_b,
                      float* __restrict__ scsh) {
    int b  = threadIdx.x & 63;
    int jw = threadIdx.x >> 6;            // 0..7
    int j  = blockIdx.x * 8 + jw;         // 0..511
    const float* wrow = mlp_w + (size_t)j * NTEMB;
    float acc = 0.f;
    for (int t = 0; t < NTEMB; ++t)
        acc = fmaf(silu_t[t * 64 + b], wrow[t], acc);
    scsh[b * 512 + j] = acc + mlp_b[j];
}

// --------------------------------------------------------------- vpass ----
// One pass over x per (b, m): accumulate ss2 (for rms inv) and
// A[h] = sum_c x[c,m] * (1+scale[c]) * Wv[h,c]  simultaneously.
// of_t[(h*256+m)*64 + b] = SC2 * (inv * A[h] + sum_c shift[c]*Wv[h,c])
__global__ void k_vpass(const float* __restrict__ x,
                        const float* __restrict__ scsh,
                        const float* __restrict__ wvp,
                        float* __restrict__ of_t) {
    int b = blockIdx.x >> 1, half = blockIdx.x & 1;
    int tid = threadIdx.x;                // 128 threads
    int m = half * 128 + tid;

    __shared__ float coef[256][8];
    __shared__ float shwv[256][8];
    __shared__ float ssh[8];

    for (int c = tid; c < 256; c += 128) {
        float sc = 1.0f + scsh[b * 512 + c];
        float sh = scsh[b * 512 + 256 + c];
#pragma unroll
        for (int h = 0; h < 8; ++h) {
            float wv = 0.f;
#pragma unroll
            for (int k = 0; k < 8; ++k) wv += wvp[(h * 8 + k) * 256 + c];
            coef[c][h] = sc * wv;
            shwv[c][h] = sh * wv;
        }
    }
    __syncthreads();
    if (tid < 8) {
        float s = 0.f;
        for (int c = 0; c < 256; ++c) s += shwv[c][tid];
        ssh[tid] = s;
    }
    __syncthreads();

    const float* xb = x + (size_t)b * NC * NHW + m;
    float A[8] = {0, 0, 0, 0, 0, 0, 0, 0};
    float ss2 = 0.f;
    for (int c = 0; c < 256; ++c) {
        float xv = xb[(size_t)c * NHW];
        ss2 = fmaf(xv, xv, ss2);
        const float4 q0 = *reinterpret_cast<const float4*>(&coef[c][0]);
        const float4 q1 = *reinterpret_cast<const float4*>(&coef[c][4]);
        A[0] = fmaf(xv, q0.x, A[0]); A[1] = fmaf(xv, q0.y, A[1]);
        A[2] = fmaf(xv, q0.z, A[2]); A[3] = fmaf(xv, q0.w, A[3]);
        A[4] = fmaf(xv, q1.x, A[4]); A[5] = fmaf(xv, q1.y, A[5]);
        A[6] = fmaf(xv, q1.z, A[6]); A[7] = fmaf(xv, q1.w, A[7]);
    }
    float inv = rsqrtf(ss2 * (1.0f / 256.0f) + EPSV);
#pragma unroll
    for (int h = 0; h < 8; ++h)
        of_t[(size_t)(h * 256 + m) * 64 + b] = SC2 * fmaf(inv, A[h], ssh[h]);
}

// --------------------------------------------------------------- gemm2 ----
// part[(ks*256+c)*64 + b] = sum_{o in ks-chunk} out_w[c,o] * of_t[o,b]
// grid: (c-tile of 4) x (k-split of 8);  lanes = b (coalesced of_t reads)
__global__ void k_gemm2(const float* __restrict__ out_w,
                        const float* __restrict__ of_t,
                        float* __restrict__ part) {
    int ct = blockIdx.x >> 3, ks = blockIdx.x & 7;
    int b = threadIdx.x & 63, cl = threadIdx.x >> 6;   // 4 waves
    int c = ct * 4 + cl;
    const float* wrow = out_w + (size_t)c * NHID + ks * 256;
    const float* ofp  = of_t + (size_t)(ks * 256) * 64 + b;
    float acc = 0.f;
    for (int o = 0; o < 256; ++o)
        acc = fmaf(wrow[o], ofp[o * 64], acc);
    part[(size_t)(ks * 256 + c) * 64 + b] = acc;
}

// ----------------------------------------------------------------- fin ----
// Per (b, spatial-chunk): reduce k-split partials -> ybar[c], per-b rms,
// g[c] = ybar*inv2*onorm[c]; then out[b,c,hw] = x[b,c,hw] + g[c].
__global__ void k_fin(const float* __restrict__ part,
                      const float* __restrict__ out_b,
                      const float* __restrict__ onorm,
                      const float* __restrict__ x,
                      float* __restrict__ out) {
    int b = blockIdx.x >> 4, ch = blockIdx.x & 15;
    int c = threadIdx.x;                  // 256 threads
    float yb = out_b[c];
#pragma unroll
    for (int ks = 0; ks < 8; ++ks)
        yb += part[(size_t)(ks * 256 + c) * 64 + b];

    __shared__ float red[256];
    __shared__ float g[256];
    red[c] = yb * yb;
    __syncthreads();
    for (int s = 128; s > 0; s >>= 1) {
        if (c < s) red[c] += red[c + s];
        __syncthreads();
    }
    float inv2 = rsqrtf(red[0] * (1.0f / 256.0f) + EPSV);
    g[c] = yb * inv2 * onorm[c];
    __syncthreads();

    const float4* x4 = reinterpret_cast<const float4*>(x) + (size_t)b * 16384;
    float4* o4 = reinterpret_cast<float4*>(out) + (size_t)b * 16384;
    for (int i = c; i < 1024; i += 256) {
        int idx = ch * 1024 + i;          // [c][hw4] within batch b
        int cc = idx >> 6;
        float4 xv = x4[idx];
        float gg = g[cc];
        o4[idx] = make_float4(xv.x + gg, xv.y + gg, xv.z + gg, xv.w + gg);
    }
}

extern "C" void kernel_launch(void* const* d_in, const int* in_sizes, int n_in,
                              void* d_out, int out_size, void* d_ws, size_t ws_size,
                              hipStream_t stream) {
    const float* x     = (const float*)d_in[0];
    const float* temb  = (const float*)d_in[1];
    const float* mlp_w = (const float*)d_in[2];
    const float* mlp_b = (const float*)d_in[3];
    const float* qkv_w = (const float*)d_in[4];
    const float* out_w = (const float*)d_in[5];
    const float* out_b = (const float*)d_in[6];
    const float* onorm = (const float*)d_in[7];

    float* ws     = (float*)d_ws;
    float* silu_t = ws;                 // 32768  (512 t x 64 b)
    float* wvp    = ws + 32768;         // 16384  (64 chunks x 256 ci)
    float* scsh   = ws + 49152;         // 32768  (64 b x 512 j)
    float* of_t   = ws + 81920;         // 131072 (2048 o x 64 b)
    float* part   = ws + 212992;        // 131072 (8 ks x 256 c x 64 b)
    float* out    = (float*)d_out;

    k_prep <<<192,  256, 0, stream>>>(temb, qkv_w, silu_t, wvp);
    k_mod  <<<64,   512, 0, stream>>>(silu_t, mlp_w, mlp_b, scsh);
    k_vpass<<<128,  128, 0, stream>>>(x, scsh, wvp, of_t);
    k_gemm2<<<512,  256, 0, stream>>>(out_w, of_t, part);
    k_fin  <<<1024, 256, 0, stream>>>(part, out_b, onorm, x, out);
}

// Round 2
// 66.462 us; speedup vs baseline: 1.0282x; 1.0282x over previous
//
#include <hip/hip_runtime.h>
#include <math.h>

// B=64, C=256, H=W=16 (HW=256), HEADS=8, HEAD_DIM=256, HID=2048, TEMB=512
// Identity: einsum 'bhnm,bhcl->bhml' contracts n and c independently =>
// softmaxes sum to 1 => q,k irrelevant; out[b, h*256+m, l] = SC^2 *
// sum_c v[b,h,c,m] (constant over spatial l), with m a spatial index.

#define NC 256
#define NHW 256
#define NHID 2048
#define NTEMB 512

static constexpr float EPSV = 1e-6f;
static constexpr float SC2 = 1.0f / 256.0f;   // SC^2, SC = 256^-0.5

// ---------------------------------------------------------------- prep ----
// blocks 0..127  : silu_t[t*64+b] = silu(time_emb[b,t])        (transposed)
// blocks 128..191: wvp[(h*8+k)*256+ci] = 32-row partial column-sum of the
//                  v-block of qkv_w
// blocks 192..319: wt[o][c] = out_w[c][o]  (64x64 LDS tile transpose)
__global__ void k_prep(const float* __restrict__ temb,
                       const float* __restrict__ qkv_w,
                       const float* __restrict__ out_w,
                       float* __restrict__ silu_t,
                       float* __restrict__ wvp,
                       float* __restrict__ wt) {
    int blk = blockIdx.x, tid = threadIdx.x;
    if (blk < 128) {
        int i = blk * 256 + tid;          // i = t*64 + b
        int t = i >> 6, b = i & 63;
        float v = temb[b * NTEMB + t];
        silu_t[i] = v / (1.0f + expf(-v));
    } else if (blk < 192) {
        int w = blk - 128;                // 0..63
        int head = w >> 3, chunk = w & 7;
        const float* base =
            qkv_w + (size_t)(2 * NHID + head * 256 + chunk * 32) * NC + tid;
        float s = 0.f;
#pragma unroll
        for (int c = 0; c < 32; ++c) s += base[c * NC];
        wvp[w * 256 + tid] = s;
    } else {
        int t = blk - 192;                // 0..127 tiles
        int ot = t >> 2, ct = t & 3;      // o-tile 0..31, c-tile 0..3
        __shared__ float tile[64][65];
        int col = tid & 63, rr = tid >> 6;
#pragma unroll
        for (int r = 0; r < 16; ++r) {
            int row = r * 4 + rr;
            tile[row][col] =
                out_w[(size_t)(ct * 64 + row) * NHID + ot * 64 + col];
        }
        __syncthreads();
#pragma unroll
        for (int r = 0; r < 16; ++r) {
            int row = r * 4 + rr;
            wt[(size_t)(ot * 64 + row) * NC + ct * 64 + col] = tile[col][row];
        }
    }
}

// ----------------------------------------------------------------- mod ----
// scsh[b*512 + j] = silu(temb[b]) . mlp_w[j] + mlp_b[j]
__global__ void k_mod(const float* __restrict__ silu_t,
                      const float* __restrict__ mlp_w,
                      const float* __restrict__ mlp_b,
                      float* __restrict__ scsh) {
    int b  = threadIdx.x & 63;
    int jw = threadIdx.x >> 6;            // 0..7
    int j  = blockIdx.x * 8 + jw;         // 0..511
    const float* wrow = mlp_w + (size_t)j * NTEMB;
    float a0 = 0.f, a1 = 0.f, a2 = 0.f, a3 = 0.f;
    for (int t = 0; t < NTEMB; t += 4) {
        a0 = fmaf(silu_t[(t + 0) * 64 + b], wrow[t + 0], a0);
        a1 = fmaf(silu_t[(t + 1) * 64 + b], wrow[t + 1], a1);
        a2 = fmaf(silu_t[(t + 2) * 64 + b], wrow[t + 2], a2);
        a3 = fmaf(silu_t[(t + 3) * 64 + b], wrow[t + 3], a3);
    }
    scsh[b * 512 + j] = (a0 + a1) + (a2 + a3) + mlp_b[j];
}

// --------------------------------------------------------------- vpass ----
// grid 256 = b(64) x m-quarter(4); 256 threads = cg(16) x mt(16), 4 m each.
// Per (b,m): A[h] = sum_c x[c,m]*(1+scale[c])*Wv[h,c], ss2 = sum_c x^2.
// of[b][h*256+m] = SC2 * (inv * A[h] + sum_c shift[c]*Wv[h,c])
__global__ void k_vpass(const float* __restrict__ x,
                        const float* __restrict__ scsh,
                        const float* __restrict__ wvp,
                        float* __restrict__ of) {
    int b = blockIdx.x >> 2, q = blockIdx.x & 3;
    int tid = threadIdx.x;
    int mt = tid & 15, cg = tid >> 4;

    __shared__ float coef[256][8];
    __shared__ float parts[4][8];
    __shared__ float ssh[8];
    __shared__ float red[4][16][36];

    {   // coef[c][h] = (1+scale)*Wv ; ssh[h] = sum_c shift*Wv
        int c = tid;
        float sc = 1.0f + scsh[b * 512 + c];
        float sh = scsh[b * 512 + 256 + c];
        float shh[8];
#pragma unroll
        for (int h = 0; h < 8; ++h) {
            float wv = 0.f;
#pragma unroll
            for (int k = 0; k < 8; ++k) wv += wvp[(h * 8 + k) * 256 + c];
            coef[c][h] = sc * wv;
            shh[h] = sh * wv;
        }
#pragma unroll
        for (int h = 0; h < 8; ++h) {
            float v = shh[h];
            v += __shfl_xor(v, 1);  v += __shfl_xor(v, 2);
            v += __shfl_xor(v, 4);  v += __shfl_xor(v, 8);
            v += __shfl_xor(v, 16); v += __shfl_xor(v, 32);
            if ((tid & 63) == 0) parts[tid >> 6][h] = v;
        }
    }
    __syncthreads();
    if (tid < 8)
        ssh[tid] = parts[0][tid] + parts[1][tid] + parts[2][tid] + parts[3][tid];
    __syncthreads();

    // main pass: acc[h*4+mi] = A, acc[32+mi] = ss2
    float acc[36];
#pragma unroll
    for (int i = 0; i < 36; ++i) acc[i] = 0.f;

    const float4* x4 =
        reinterpret_cast<const float4*>(x) + (size_t)b * 16384 + q * 16 + mt;
    for (int ci = 0; ci < 16; ++ci) {
        int c = cg * 16 + ci;
        float4 xv = x4[(size_t)c * 64];
        float xa[4] = {xv.x, xv.y, xv.z, xv.w};
        float4 cf0 = *reinterpret_cast<const float4*>(&coef[c][0]);
        float4 cf1 = *reinterpret_cast<const float4*>(&coef[c][4]);
        float cf[8] = {cf0.x, cf0.y, cf0.z, cf0.w, cf1.x, cf1.y, cf1.z, cf1.w};
#pragma unroll
        for (int h = 0; h < 8; ++h)
#pragma unroll
            for (int mi = 0; mi < 4; ++mi)
                acc[h * 4 + mi] = fmaf(xa[mi], cf[h], acc[h * 4 + mi]);
#pragma unroll
        for (int mi = 0; mi < 4; ++mi)
            acc[32 + mi] = fmaf(xa[mi], xa[mi], acc[32 + mi]);
    }

    // reduce over 4 cgs within wave (lane bits 4,5), then over 4 waves
#pragma unroll
    for (int i = 0; i < 36; ++i) {
        acc[i] += __shfl_xor(acc[i], 16);
        acc[i] += __shfl_xor(acc[i], 32);
    }
    int wv_ = tid >> 6;
    if ((tid & 63) < 16) {
#pragma unroll
        for (int i = 0; i < 36; ++i) red[wv_][mt][i] = acc[i];
    }
    __syncthreads();

    if (tid < 16) {
        float fin[36];
#pragma unroll
        for (int i = 0; i < 36; ++i)
            fin[i] = red[0][tid][i] + red[1][tid][i] +
                     red[2][tid][i] + red[3][tid][i];
        float invv[4];
#pragma unroll
        for (int mi = 0; mi < 4; ++mi)
            invv[mi] = rsqrtf(fin[32 + mi] * (1.0f / 256.0f) + EPSV);
        float4* o4 = reinterpret_cast<float4*>(of);
#pragma unroll
        for (int h = 0; h < 8; ++h) {
            float4 r;
            r.x = SC2 * fmaf(invv[0], fin[h * 4 + 0], ssh[h]);
            r.y = SC2 * fmaf(invv[1], fin[h * 4 + 1], ssh[h]);
            r.z = SC2 * fmaf(invv[2], fin[h * 4 + 2], ssh[h]);
            r.w = SC2 * fmaf(invv[3], fin[h * 4 + 3], ssh[h]);
            o4[b * 512 + h * 64 + q * 16 + tid] = r;
        }
    }
}

// --------------------------------------------------------------- gemm2 ----
// per-b: ybar[c] = out_b[c] + sum_o wt[o][c]*of[b][o]; rms over c;
// g[b][c] = ybar*inv2*onorm[c].  512 threads = c(256) x o-half(2).
__global__ void k_gemm2(const float* __restrict__ wt,
                        const float* __restrict__ of,
                        const float* __restrict__ out_b,
                        const float* __restrict__ onorm,
                        float* __restrict__ g) {
    int b = blockIdx.x, tid = threadIdx.x;
    int c = tid & 255, os = tid >> 8;
    __shared__ float ofs[2048];
    __shared__ float padd[2][256];
    __shared__ float wred[8];

    for (int i = tid; i < 2048; i += 512) ofs[i] = of[b * 2048 + i];
    __syncthreads();

    const float* wp = wt + (size_t)(os * 1024) * NC + c;
    const float* op = ofs + os * 1024;
    float a0 = 0.f, a1 = 0.f, a2 = 0.f, a3 = 0.f;
    for (int o = 0; o < 1024; o += 4) {
        a0 = fmaf(wp[(o + 0) * NC], op[o + 0], a0);
        a1 = fmaf(wp[(o + 1) * NC], op[o + 1], a1);
        a2 = fmaf(wp[(o + 2) * NC], op[o + 2], a2);
        a3 = fmaf(wp[(o + 3) * NC], op[o + 3], a3);
    }
    padd[os][c] = (a0 + a1) + (a2 + a3);
    __syncthreads();

    float yb = 0.f;
    if (os == 0) yb = out_b[c] + padd[0][c] + padd[1][c];
    float v = yb * yb;
    v += __shfl_xor(v, 1);  v += __shfl_xor(v, 2);
    v += __shfl_xor(v, 4);  v += __shfl_xor(v, 8);
    v += __shfl_xor(v, 16); v += __shfl_xor(v, 32);
    if ((tid & 63) == 0) wred[tid >> 6] = v;
    __syncthreads();
    float tot = wred[0] + wred[1] + wred[2] + wred[3] +
                wred[4] + wred[5] + wred[6] + wred[7];
    if (os == 0) {
        float inv2 = rsqrtf(tot * (1.0f / 256.0f) + EPSV);
        g[b * 256 + c] = yb * inv2 * onorm[c];
    }
}

// ----------------------------------------------------------------- fin ----
// pure stream: out[b,c,hw] = x[b,c,hw] + g[b,c]
__global__ void k_fin(const float* __restrict__ g,
                      const float* __restrict__ x,
                      float* __restrict__ out) {
    int b = blockIdx.x >> 4, ch = blockIdx.x & 15;
    int tid = threadIdx.x;
    __shared__ float gs[256];
    gs[tid] = g[b * 256 + tid];
    __syncthreads();
    const float4* x4 =
        reinterpret_cast<const float4*>(x) + (size_t)b * 16384 + ch * 1024;
    float4* o4 = reinterpret_cast<float4*>(out) + (size_t)b * 16384 + ch * 1024;
#pragma unroll
    for (int i = tid; i < 1024; i += 256) {
        int cc = (ch * 1024 + i) >> 6;
        float4 xv = x4[i];
        float gg = gs[cc];
        o4[i] = make_float4(xv.x + gg, xv.y + gg, xv.z + gg, xv.w + gg);
    }
}

extern "C" void kernel_launch(void* const* d_in, const int* in_sizes, int n_in,
                              void* d_out, int out_size, void* d_ws, size_t ws_size,
                              hipStream_t stream) {
    const float* x     = (const float*)d_in[0];
    const float* temb  = (const float*)d_in[1];
    const float* mlp_w = (const float*)d_in[2];
    const float* mlp_b = (const float*)d_in[3];
    const float* qkv_w = (const float*)d_in[4];
    const float* out_w = (const float*)d_in[5];
    const float* out_b = (const float*)d_in[6];
    const float* onorm = (const float*)d_in[7];

    float* ws     = (float*)d_ws;
    float* silu_t = ws;                  // 32768   (512 t x 64 b)
    float* wvp    = ws + 32768;          // 16384   (64 chunks x 256 ci)
    float* scsh   = ws + 49152;          // 32768   (64 b x 512 j)
    float* of     = ws + 81920;          // 131072  (64 b x 2048 o)
    float* wt     = ws + 212992;         // 524288  (2048 o x 256 c)
    float* g      = ws + 737280;         // 16384   (64 b x 256 c)
    float* out    = (float*)d_out;

    k_prep <<<320,  256, 0, stream>>>(temb, qkv_w, out_w, silu_t, wvp, wt);
    k_mod  <<<64,   512, 0, stream>>>(silu_t, mlp_w, mlp_b, scsh);
    k_vpass<<<256,  256, 0, stream>>>(x, scsh, wvp, of);
    k_gemm2<<<64,   512, 0, stream>>>(wt, of, out_b, onorm, g);
    k_fin  <<<1024, 256, 0, stream>>>(g, x, out);
}